// Round 10
// baseline (312.534 us; speedup 1.0000x reference)
//
#include <hip/hip_runtime.h>
#include <cstdint>
#include <cstddef>

#define NN 50000
#define NE 1600000
#define NG 64
#define NCB 391          // coarse buckets: dst>>7, 128 nodes each
#define HB 98            // histogram blocks co-dispatched with gemm1
#define EPB_A 8192       // edges per parta block
#define CAP_B 8192       // LDS edge capacity in partb
#define NPH 7            // src-range phases (src>>13, 50000/8192 -> 0..6)

// ---- bf16 helpers ----
__device__ __forceinline__ float bflo(unsigned u) { return __uint_as_float(u << 16); }
__device__ __forceinline__ float bfhi(unsigned u) { return __uint_as_float(u & 0xffff0000u); }
__device__ __forceinline__ unsigned f2bf(float f) {  // RTNE, returns low 16 bits
    unsigned u = __float_as_uint(f);
    return (u + 0x7fffu + ((u >> 16) & 1u)) >> 16;
}
__device__ __forceinline__ float rdlane_f(float v, int l) {
    return __uint_as_float((unsigned)__builtin_amdgcn_readlane((int)__float_as_uint(v), l));
}

// ---- fused tiled GEMM + attention logits (+ optional co-dispatched coarse hist) ----
template <int FIN, int FOUT, bool HIST>
__global__ void gemm_att_k(const float* __restrict__ A, const float* __restrict__ W,
                           const float* __restrict__ a_src, const float* __restrict__ a_dst,
                           unsigned* __restrict__ Hb, float* __restrict__ as_,
                           float* __restrict__ ad_, int gemmBlocks,
                           const int* __restrict__ edst, int* __restrict__ gcount) {
    __shared__ float Wl[FIN * FOUT];
    __shared__ float Al[32 * FIN];
    __shared__ int hh[NCB];
    int tid = threadIdx.x;
    if (HIST && blockIdx.x >= gemmBlocks) {
        int bid = blockIdx.x - gemmBlocks;
        for (int i = tid; i < NCB; i += 256) hh[i] = 0;
        __syncthreads();
        const int total4 = NE / 4;
        for (int i = bid * 256 + tid; i < total4; i += HB * 256) {
            int4 d = ((const int4*)edst)[i];
            atomicAdd(&hh[d.x >> 7], 1);
            atomicAdd(&hh[d.y >> 7], 1);
            atomicAdd(&hh[d.z >> 7], 1);
            atomicAdd(&hh[d.w >> 7], 1);
        }
        __syncthreads();
        for (int i = tid; i < NCB; i += 256)
            if (hh[i]) atomicAdd(&gcount[i], hh[i]);
        return;
    }
    const int RPB = 32;
    const int CP = FOUT / 2;
    const int CLANES = 256 / CP;
    const int RL = RPB / CLANES;
    for (int i = tid; i < (FIN * FOUT) / 4; i += 256)
        ((float4*)Wl)[i] = ((const float4*)W)[i];
    int rowbase = blockIdx.x * RPB;
    int nrows = min(RPB, NN - rowbase);
    int nel4 = (nrows * FIN) / 4;
    const float4* Asrc = (const float4*)(A + (size_t)rowbase * FIN);
    for (int i = tid; i < nel4; i += 256) ((float4*)Al)[i] = Asrc[i];
    __syncthreads();
    int c2 = tid % CP;
    int rb = tid / CP;
    float acc0[RL], acc1[RL];
#pragma unroll
    for (int r = 0; r < RL; ++r) { acc0[r] = 0.f; acc1[r] = 0.f; }
#pragma unroll 4
    for (int k = 0; k < FIN; ++k) {
        float w0 = Wl[k * FOUT + 2 * c2];
        float w1 = Wl[k * FOUT + 2 * c2 + 1];
#pragma unroll
        for (int r = 0; r < RL; ++r) {
            float a = Al[(rb + r * CLANES) * FIN + k];
            acc0[r] += a * w0;
            acc1[r] += a * w1;
        }
    }
    float2 asrc2 = ((const float2*)a_src)[c2];
    float2 adst2 = ((const float2*)a_dst)[c2];
#pragma unroll
    for (int r = 0; r < RL; ++r) {
        int row = rowbase + rb + r * CLANES;
        float p1 = acc0[r] * asrc2.x + acc1[r] * asrc2.y;
        float p2 = acc0[r] * adst2.x + acc1[r] * adst2.y;
#pragma unroll
        for (int o = CP >> 1; o; o >>= 1) {
            p1 += __shfl_xor(p1, o, CP);
            p2 += __shfl_xor(p2, o, CP);
        }
        if (row < NN) {
            Hb[(size_t)row * CP + c2] = f2bf(acc0[r]) | (f2bf(acc1[r]) << 16);
            if (c2 == 0) { as_[row] = p1; ad_[row] = p2; }
        }
    }
}

// ---- scan coarse counts -> cbase; init gcur (2 entries per thread) ----
__global__ void cscan_k(const int* __restrict__ gcount, int* __restrict__ cbase,
                        int* __restrict__ gcur) {
    __shared__ int part[256];
    int tid = threadIdx.x;
    int i0 = 2 * tid, i1 = 2 * tid + 1;
    int v0 = (i0 < NCB) ? gcount[i0] : 0;
    int v1 = (i1 < NCB) ? gcount[i1] : 0;
    part[tid] = v0 + v1;
    __syncthreads();
    for (int off = 1; off < 256; off <<= 1) {
        int v = (tid >= off) ? part[tid - off] : 0;
        __syncthreads();
        part[tid] += v;
        __syncthreads();
    }
    int run = tid ? part[tid - 1] : 0;
    if (i0 < NCB) { cbase[i0] = run; gcur[i0] = run; run += v0; }
    if (i1 < NCB) { cbase[i1] = run; gcur[i1] = run; run += v1; }
    if (tid == 255) cbase[NCB] = part[255];
}

// ---- pass A: partition edges into coarse buckets with dense LDS-staged flushes ----
__global__ void parta_k(const int* __restrict__ esrc, const int* __restrict__ edst,
                        int* __restrict__ gcur, int* __restrict__ pk_g) {
    __shared__ int cnt[NCB];
    __shared__ int base[NCB];
    __shared__ int cur[NCB];
    __shared__ int gposs[NCB];
    __shared__ int sc[256];
    __shared__ int lpk[EPB_A];
    int tid = threadIdx.x;
    int e0 = blockIdx.x * EPB_A;
    int e1 = min(e0 + EPB_A, NE);
    for (int i = tid; i < NCB; i += 256) cnt[i] = 0;
    __syncthreads();
    for (int i = e0 / 4 + tid; i < e1 / 4; i += 256) {
        int4 d = ((const int4*)edst)[i];
        atomicAdd(&cnt[d.x >> 7], 1);
        atomicAdd(&cnt[d.y >> 7], 1);
        atomicAdd(&cnt[d.z >> 7], 1);
        atomicAdd(&cnt[d.w >> 7], 1);
    }
    __syncthreads();
    int i0 = 2 * tid, i1 = 2 * tid + 1;
    int c0 = (i0 < NCB) ? cnt[i0] : 0;
    int c1 = (i1 < NCB) ? cnt[i1] : 0;
    sc[tid] = c0 + c1;
    __syncthreads();
    for (int off = 1; off < 256; off <<= 1) {
        int v = (tid >= off) ? sc[tid - off] : 0;
        __syncthreads();
        sc[tid] += v;
        __syncthreads();
    }
    int run = tid ? sc[tid - 1] : 0;
    if (i0 < NCB) {
        base[i0] = run; cur[i0] = run;
        gposs[i0] = atomicAdd(&gcur[i0], c0);
        run += c0;
    }
    if (i1 < NCB) {
        base[i1] = run; cur[i1] = run;
        gposs[i1] = atomicAdd(&gcur[i1], c1);
        run += c1;
    }
    __syncthreads();
    for (int i = e0 / 4 + tid; i < e1 / 4; i += 256) {
        int4 d = ((const int4*)edst)[i];
        int4 s = ((const int4*)esrc)[i];
        lpk[atomicAdd(&cur[d.x >> 7], 1)] = s.x | ((d.x & 127) << 17);
        lpk[atomicAdd(&cur[d.y >> 7], 1)] = s.y | ((d.y & 127) << 17);
        lpk[atomicAdd(&cur[d.z >> 7], 1)] = s.z | ((d.z & 127) << 17);
        lpk[atomicAdd(&cur[d.w >> 7], 1)] = s.w | ((d.w & 127) << 17);
    }
    __syncthreads();
    int wid = tid >> 6, lane = tid & 63;
    for (int c = wid; c < NCB; c += 4) {
        int n = cnt[c], gb = gposs[c], lb = base[c];
        for (int i = lane; i < n; i += 64) pk_g[gb + i] = lpk[lb + i];
    }
}

// ---- pass B: per coarse bucket (128 nodes), build fine CSR + offsets in LDS ----
// Scatter happens in NPH sequential phases keyed on src>>13 so each node's
// final list is clustered by src range -> gather locality in node_agg.
__global__ void partb_k(const int* __restrict__ pk_g, const int* __restrict__ cbase,
                        int* __restrict__ offsets, int* __restrict__ csr) {
    __shared__ int cnt[128];
    __shared__ int sc[256];
    __shared__ int lpk[CAP_B];
    int b = blockIdx.x, tid = threadIdx.x;
    int ebeg = cbase[b], eend = cbase[b + 1], n = eend - ebeg;
    int nbeg = b * 128;
    int ncnt = min(128, NN - nbeg);
    if (tid < 128) cnt[tid] = 0;
    __syncthreads();
    bool fits = (n <= CAP_B);
    if (fits) {
        for (int i = tid; i < n; i += 256) {
            int p = pk_g[ebeg + i];
            lpk[i] = p;
            atomicAdd(&cnt[p >> 17], 1);
        }
    } else {
        for (int i = tid; i < n; i += 256) atomicAdd(&cnt[pk_g[ebeg + i] >> 17], 1);
    }
    __syncthreads();
    int c0 = (tid < 128) ? cnt[tid] : 0;
    sc[tid] = c0;
    __syncthreads();
    for (int off = 1; off < 128; off <<= 1) {
        int v = (tid >= off && tid < 128) ? sc[tid - off] : 0;
        __syncthreads();
        if (tid < 128) sc[tid] += v;
        __syncthreads();
    }
    int excl = (tid < 128) ? sc[tid] - c0 : 0;
    if (tid < ncnt) offsets[nbeg + tid] = ebeg + excl;
    if (b == NCB - 1 && tid == 0) offsets[NN] = eend;
    __syncthreads();
    if (tid < 128) cnt[tid] = ebeg + excl;   // global cursor per local node
    __syncthreads();
    if (fits) {
        // phased scatter: src-range-major within each dst list
        for (int ph = 0; ph < NPH; ++ph) {
            for (int i = tid; i < n; i += 256) {
                int p = lpk[i];
                int src = p & 0x1FFFF;
                if ((src >> 13) == ph)
                    csr[atomicAdd(&cnt[p >> 17], 1)] = src;
            }
            __syncthreads();
        }
    } else {
        for (int i = tid; i < n; i += 256) {
            int p = pk_g[ebeg + i];
            csr[atomicAdd(&cnt[p >> 17], 1)] = p & 0x1FFFF;
        }
    }
}

// ---- fused per-node GAT aggregation: ONE NODE PER WAVE, single pass (no max) ----
template <int F, bool RELU>
__global__ void node_agg_k(const int* __restrict__ off, const int* __restrict__ csr,
                           const float* __restrict__ as_, const float* __restrict__ ad_,
                           const unsigned* __restrict__ Hb2,
                           const float* __restrict__ b, float* __restrict__ O) {
    int lane = threadIdx.x & 63;
    int node = blockIdx.x * (blockDim.x >> 6) + (threadIdx.x >> 6);
    if (node >= NN) return;
    int beg = off[node], end = off[node + 1];
    float adn = ad_[node];
    float vself = as_[node] + adn;
    vself = vself > 0.f ? vself : 0.2f * vself;
    float eself = __expf(vself);
    float lsum = 0.f;

    if constexpr (F == 128) {
        unsigned hbs = Hb2[(size_t)node * 64 + lane];
        float accx = eself * bflo(hbs);
        float accy = eself * bfhi(hbs);
        for (int i0 = beg; i0 < end; i0 += 64) {
            int idx = i0 + lane;
            bool ok = idx < end;
            int s = ok ? csr[idx] : 0;
            float v = as_[s] + adn;
            v = v > 0.f ? v : 0.2f * v;
            float ee = ok ? __expf(v) : 0.f;
            lsum += ee;
            int rem = min(end - i0, 64);
            int j = 0;
            for (; j + 8 <= rem; j += 8) {
#pragma unroll
                for (int k = 0; k < 8; ++k) {
                    int s2 = __builtin_amdgcn_readlane(s, j + k);
                    float ee2 = rdlane_f(ee, j + k);
                    unsigned hb = (Hb2 + (size_t)s2 * 64)[lane];
                    accx += ee2 * bflo(hb);
                    accy += ee2 * bfhi(hb);
                }
            }
            for (; j < rem; ++j) {
                int s2 = __builtin_amdgcn_readlane(s, j);
                float ee2 = rdlane_f(ee, j);
                unsigned hb = (Hb2 + (size_t)s2 * 64)[lane];
                accx += ee2 * bflo(hb);
                accy += ee2 * bfhi(hb);
            }
        }
#pragma unroll
        for (int o = 32; o; o >>= 1) lsum += __shfl_xor(lsum, o);
        float inv = 1.f / (lsum + eself + 1e-16f);
        float2 bb = ((const float2*)b)[lane];
        float ox = accx * inv + bb.x;
        float oy = accy * inv + bb.y;
        if (RELU) { ox = fmaxf(ox, 0.f); oy = fmaxf(oy, 0.f); }
        ((float2*)O)[(size_t)node * 64 + lane] = make_float2(ox, oy);
    } else if constexpr (F == 64) {
        const unsigned short* Hs = (const unsigned short*)Hb2;
        float acc = eself * bflo((unsigned)Hs[(size_t)node * 64 + lane]);
        for (int i0 = beg; i0 < end; i0 += 64) {
            int idx = i0 + lane;
            bool ok = idx < end;
            int s = ok ? csr[idx] : 0;
            float v = as_[s] + adn;
            v = v > 0.f ? v : 0.2f * v;
            float ee = ok ? __expf(v) : 0.f;
            lsum += ee;
            int rem = min(end - i0, 64);
            int j = 0;
            for (; j + 8 <= rem; j += 8) {
#pragma unroll
                for (int k = 0; k < 8; ++k) {
                    int s2 = __builtin_amdgcn_readlane(s, j + k);
                    float ee2 = rdlane_f(ee, j + k);
                    acc += ee2 * bflo((unsigned)(Hs + (size_t)s2 * 64)[lane]);
                }
            }
            for (; j < rem; ++j) {
                int s2 = __builtin_amdgcn_readlane(s, j);
                float ee2 = rdlane_f(ee, j);
                acc += ee2 * bflo((unsigned)(Hs + (size_t)s2 * 64)[lane]);
            }
        }
#pragma unroll
        for (int o = 32; o; o >>= 1) lsum += __shfl_xor(lsum, o);
        float inv = 1.f / (lsum + eself + 1e-16f);
        float ox = acc * inv + b[lane];
        if (RELU) ox = fmaxf(ox, 0.f);
        O[(size_t)node * 64 + lane] = ox;
    } else {  // F == 32
        const int GRP = 16, EPG = 4, U = 2;
        int sg = lane / GRP;
        int cl = lane % GRP;
        unsigned hbs = Hb2[(size_t)node * GRP + cl];
        float accx = (sg == 0) ? eself * bflo(hbs) : 0.f;
        float accy = (sg == 0) ? eself * bfhi(hbs) : 0.f;
        for (int i0 = beg; i0 < end; i0 += 64) {
            int idx = i0 + lane;
            bool ok = idx < end;
            int s = ok ? csr[idx] : 0;
            float v = as_[s] + adn;
            v = v > 0.f ? v : 0.2f * v;
            float ee = ok ? __expf(v) : 0.f;
            lsum += ee;
            int rem = min(end - i0, 64);
            int nj = (rem + EPG - 1) / EPG;
            nj = (nj + U - 1) & ~(U - 1);
            for (int j = 0; j < nj; j += U) {
#pragma unroll
                for (int k = 0; k < U; ++k) {
                    int pos = (j + k) * EPG + sg;
                    int s2 = __shfl(s, pos);
                    float ee2 = __shfl(ee, pos);
                    unsigned hb = Hb2[(size_t)s2 * GRP + cl];
                    accx += ee2 * bflo(hb);
                    accy += ee2 * bfhi(hb);
                }
            }
        }
#pragma unroll
        for (int o = 32; o; o >>= 1) lsum += __shfl_xor(lsum, o);
        float sum = lsum + eself;
#pragma unroll
        for (int o = 32; o >= GRP; o >>= 1) {
            accx += __shfl_xor(accx, o);
            accy += __shfl_xor(accy, o);
        }
        if (sg == 0) {
            float inv = 1.f / (sum + 1e-16f);
            float2 bb = ((const float2*)b)[cl];
            float ox = accx * inv + bb.x;
            float oy = accy * inv + bb.y;
            if (RELU) { ox = fmaxf(ox, 0.f); oy = fmaxf(oy, 0.f); }
            ((float2*)O)[(size_t)node * GRP + cl] = make_float2(ox, oy);
        }
    }
}

// ---- global_add_pool ----
__global__ void pool_k(const float* __restrict__ O, const int* __restrict__ batch,
                       float* __restrict__ g, int nodes_per_block) {
    __shared__ float acc[NG * 128];
    int c = threadIdx.x;
    for (int i = 0; i < NG; ++i) acc[i * 128 + c] = 0.f;
    int start = blockIdx.x * nodes_per_block;
    int end = min(start + nodes_per_block, NN);
    int gmin = NG - 1, gmax = 0;
    for (int nd = start; nd < end; ++nd) {
        int gg = batch[nd];
        gmin = min(gmin, gg);
        gmax = max(gmax, gg);
        acc[gg * 128 + c] += O[(size_t)nd * 128 + c];
    }
    for (int i = gmin; i <= gmax; ++i) atomicAdd(g + i * 128 + c, acc[i * 128 + c]);
}

// ---- head ----
__global__ void head_k(const float* __restrict__ g, const float* __restrict__ l1W,
                       const float* __restrict__ l1b, const float* __restrict__ l2W,
                       const float* __restrict__ l2b, float* __restrict__ out) {
    __shared__ float h1[NG * 32];
    __shared__ float o[NG * 10];
    int tid = threadIdx.x;
    for (int idx = tid; idx < NG * 32; idx += 256) {
        int r = idx / 32, c = idx % 32;
        float acc = l1b[c];
        for (int k = 0; k < 128; ++k) acc += g[r * 128 + k] * l1W[k * 32 + c];
        h1[idx] = fmaxf(acc, 0.f);
    }
    __syncthreads();
    for (int idx = tid; idx < NG * 10; idx += 256) {
        int r = idx / 10, c = idx % 10;
        float acc = l2b[c];
        for (int k = 0; k < 32; ++k) acc += h1[r * 32 + k] * l2W[k * 10 + c];
        o[idx] = acc;
    }
    __syncthreads();
    if (tid < 10) {
        float mx = -1e30f;
        for (int r = 0; r < NG; ++r) mx = fmaxf(mx, o[r * 10 + tid]);
        float sum = 0.f;
        for (int r = 0; r < NG; ++r) sum += __expf(o[r * 10 + tid] - mx);
        float lse = mx + logf(sum);
        for (int r = 0; r < NG; ++r) out[r * 10 + tid] = o[r * 10 + tid] - lse;
    }
}

extern "C" void kernel_launch(void* const* d_in, const int* in_sizes, int n_in,
                              void* d_out, int out_size, void* d_ws, size_t ws_size,
                              hipStream_t stream) {
    const float* x   = (const float*)d_in[0];
    const int* ei    = (const int*)d_in[1];
    const int* batch = (const int*)d_in[2];
    const float* W1 = (const float*)d_in[3];
    const float* as1 = (const float*)d_in[4];
    const float* ad1 = (const float*)d_in[5];
    const float* b1 = (const float*)d_in[6];
    const float* W2 = (const float*)d_in[7];
    const float* as2 = (const float*)d_in[8];
    const float* ad2 = (const float*)d_in[9];
    const float* b2 = (const float*)d_in[10];
    const float* W3 = (const float*)d_in[11];
    const float* as3 = (const float*)d_in[12];
    const float* ad3 = (const float*)d_in[13];
    const float* b3 = (const float*)d_in[14];
    const float* l1W = (const float*)d_in[15];
    const float* l1b = (const float*)d_in[16];
    const float* l2W = (const float*)d_in[17];
    const float* l2b = (const float*)d_in[18];
    float* out = (float*)d_out;

    const int* esrc = ei;
    const int* edst = ei + NE;

    char* ws = (char*)d_ws;
    float* B0 = (float*)ws;                            // NN*128 f32
    float* B1 = B0 + (size_t)NN * 128;                 // NN*64 f32
    unsigned* Hb = (unsigned*)(B1 + (size_t)NN * 64);  // NN*64 uints (NN*128 bf16)
    float* as_ = (float*)(Hb + (size_t)NN * 64);       // NN
    float* ad_ = as_ + NN;                             // NN
    int* gcount = (int*)(ad_ + NN);                    // NCB   \ one memset
    float* g    = (float*)(gcount + NCB);              // NG*128/
    int* cbase  = (int*)(g + NG * 128);                // NCB+1
    int* gcur   = cbase + NCB + 1;                     // NCB
    int* offsets = gcur + NCB + 2;                     // NN+1
    int* csr    = offsets + NN + 1;                    // NE
    int* pk     = csr + NE;                            // NE staging
    const int GEMM_BLOCKS = (NN + 31) / 32;            // 1563

    // zero gcount + g in one shot (contiguous)
    hipMemsetAsync(gcount, 0, (NCB + NG * 128) * 4, stream);

    // layer-1 GEMM+logits co-dispatched with coarse histogram
    gemm_att_k<128, 32, true><<<GEMM_BLOCKS + HB, 256, 0, stream>>>(
        x, W1, as1, ad1, Hb, as_, ad_, GEMM_BLOCKS, edst, gcount);
    cscan_k<<<1, 256, 0, stream>>>(gcount, cbase, gcur);
    parta_k<<<(NE + EPB_A - 1) / EPB_A, 256, 0, stream>>>(esrc, edst, gcur, pk);
    partb_k<<<NCB, 256, 0, stream>>>(pk, cbase, offsets, csr);
    node_agg_k<32, true><<<(NN + 3) / 4, 256, 0, stream>>>(offsets, csr, as_, ad_, Hb, b1, B0);

    gemm_att_k<32, 64, false><<<GEMM_BLOCKS, 256, 0, stream>>>(
        B0, W2, as2, ad2, Hb, as_, ad_, GEMM_BLOCKS, nullptr, nullptr);
    node_agg_k<64, true><<<(NN + 3) / 4, 256, 0, stream>>>(offsets, csr, as_, ad_, Hb, b2, B1);

    gemm_att_k<64, 128, false><<<GEMM_BLOCKS, 256, 0, stream>>>(
        B1, W3, as3, ad3, Hb, as_, ad_, GEMM_BLOCKS, nullptr, nullptr);
    node_agg_k<128, false><<<(NN + 3) / 4, 256, 0, stream>>>(offsets, csr, as_, ad_, Hb, b3, B0);

    pool_k<<<(NN + 127) / 128, 128, 0, stream>>>(B0, batch, g, 128);
    head_k<<<1, 256, 0, stream>>>(g, l1W, l1b, l2W, l2b, out);
}

// Round 11
// 297.475 us; speedup vs baseline: 1.0506x; 1.0506x over previous
//
#include <hip/hip_runtime.h>
#include <cstdint>
#include <cstddef>

#define NN 50000
#define NE 1600000
#define NG 64
#define NCB 391          // coarse buckets: dst>>7, 128 nodes each
#define HB 98            // histogram blocks co-dispatched with gemm1
#define EPB_A 8192       // edges per parta block
#define CAP_B 8192       // LDS edge capacity in partb

// ---- bf16 helpers ----
__device__ __forceinline__ float bflo(unsigned u) { return __uint_as_float(u << 16); }
__device__ __forceinline__ float bfhi(unsigned u) { return __uint_as_float(u & 0xffff0000u); }
__device__ __forceinline__ unsigned f2bf(float f) {  // RTNE, returns low 16 bits
    unsigned u = __float_as_uint(f);
    return (u + 0x7fffu + ((u >> 16) & 1u)) >> 16;
}
__device__ __forceinline__ float rdlane_f(float v, int l) {
    return __uint_as_float((unsigned)__builtin_amdgcn_readlane((int)__float_as_uint(v), l));
}

// ---- fused tiled GEMM + attention logits (+ optional co-dispatched coarse hist) ----
template <int FIN, int FOUT, bool HIST>
__global__ void gemm_att_k(const float* __restrict__ A, const float* __restrict__ W,
                           const float* __restrict__ a_src, const float* __restrict__ a_dst,
                           unsigned* __restrict__ Hb, float* __restrict__ as_,
                           float* __restrict__ ad_, int gemmBlocks,
                           const int* __restrict__ edst, int* __restrict__ gcount) {
    __shared__ float Wl[FIN * FOUT];
    __shared__ float Al[32 * FIN];
    __shared__ int hh[NCB];
    int tid = threadIdx.x;
    if (HIST && blockIdx.x >= gemmBlocks) {
        int bid = blockIdx.x - gemmBlocks;
        for (int i = tid; i < NCB; i += 256) hh[i] = 0;
        __syncthreads();
        const int total4 = NE / 4;
        for (int i = bid * 256 + tid; i < total4; i += HB * 256) {
            int4 d = ((const int4*)edst)[i];
            atomicAdd(&hh[d.x >> 7], 1);
            atomicAdd(&hh[d.y >> 7], 1);
            atomicAdd(&hh[d.z >> 7], 1);
            atomicAdd(&hh[d.w >> 7], 1);
        }
        __syncthreads();
        for (int i = tid; i < NCB; i += 256)
            if (hh[i]) atomicAdd(&gcount[i], hh[i]);
        return;
    }
    const int RPB = 32;
    const int CP = FOUT / 2;
    const int CLANES = 256 / CP;
    const int RL = RPB / CLANES;
    for (int i = tid; i < (FIN * FOUT) / 4; i += 256)
        ((float4*)Wl)[i] = ((const float4*)W)[i];
    int rowbase = blockIdx.x * RPB;
    int nrows = min(RPB, NN - rowbase);
    int nel4 = (nrows * FIN) / 4;
    const float4* Asrc = (const float4*)(A + (size_t)rowbase * FIN);
    for (int i = tid; i < nel4; i += 256) ((float4*)Al)[i] = Asrc[i];
    __syncthreads();
    int c2 = tid % CP;
    int rb = tid / CP;
    float acc0[RL], acc1[RL];
#pragma unroll
    for (int r = 0; r < RL; ++r) { acc0[r] = 0.f; acc1[r] = 0.f; }
#pragma unroll 4
    for (int k = 0; k < FIN; ++k) {
        float w0 = Wl[k * FOUT + 2 * c2];
        float w1 = Wl[k * FOUT + 2 * c2 + 1];
#pragma unroll
        for (int r = 0; r < RL; ++r) {
            float a = Al[(rb + r * CLANES) * FIN + k];
            acc0[r] += a * w0;
            acc1[r] += a * w1;
        }
    }
    float2 asrc2 = ((const float2*)a_src)[c2];
    float2 adst2 = ((const float2*)a_dst)[c2];
#pragma unroll
    for (int r = 0; r < RL; ++r) {
        int row = rowbase + rb + r * CLANES;
        float p1 = acc0[r] * asrc2.x + acc1[r] * asrc2.y;
        float p2 = acc0[r] * adst2.x + acc1[r] * adst2.y;
#pragma unroll
        for (int o = CP >> 1; o; o >>= 1) {
            p1 += __shfl_xor(p1, o, CP);
            p2 += __shfl_xor(p2, o, CP);
        }
        if (row < NN) {
            Hb[(size_t)row * CP + c2] = f2bf(acc0[r]) | (f2bf(acc1[r]) << 16);
            if (c2 == 0) { as_[row] = p1; ad_[row] = p2; }
        }
    }
}

// ---- scan coarse counts -> cbase; init gcur (2 entries per thread) ----
__global__ void cscan_k(const int* __restrict__ gcount, int* __restrict__ cbase,
                        int* __restrict__ gcur) {
    __shared__ int part[256];
    int tid = threadIdx.x;
    int i0 = 2 * tid, i1 = 2 * tid + 1;
    int v0 = (i0 < NCB) ? gcount[i0] : 0;
    int v1 = (i1 < NCB) ? gcount[i1] : 0;
    part[tid] = v0 + v1;
    __syncthreads();
    for (int off = 1; off < 256; off <<= 1) {
        int v = (tid >= off) ? part[tid - off] : 0;
        __syncthreads();
        part[tid] += v;
        __syncthreads();
    }
    int run = tid ? part[tid - 1] : 0;
    if (i0 < NCB) { cbase[i0] = run; gcur[i0] = run; run += v0; }
    if (i1 < NCB) { cbase[i1] = run; gcur[i1] = run; run += v1; }
    if (tid == 255) cbase[NCB] = part[255];
}

// ---- pass A: partition edges into coarse buckets with dense LDS-staged flushes ----
__global__ void parta_k(const int* __restrict__ esrc, const int* __restrict__ edst,
                        int* __restrict__ gcur, int* __restrict__ pk_g) {
    __shared__ int cnt[NCB];
    __shared__ int base[NCB];
    __shared__ int cur[NCB];
    __shared__ int gposs[NCB];
    __shared__ int sc[256];
    __shared__ int lpk[EPB_A];
    int tid = threadIdx.x;
    int e0 = blockIdx.x * EPB_A;
    int e1 = min(e0 + EPB_A, NE);
    for (int i = tid; i < NCB; i += 256) cnt[i] = 0;
    __syncthreads();
    for (int i = e0 / 4 + tid; i < e1 / 4; i += 256) {
        int4 d = ((const int4*)edst)[i];
        atomicAdd(&cnt[d.x >> 7], 1);
        atomicAdd(&cnt[d.y >> 7], 1);
        atomicAdd(&cnt[d.z >> 7], 1);
        atomicAdd(&cnt[d.w >> 7], 1);
    }
    __syncthreads();
    int i0 = 2 * tid, i1 = 2 * tid + 1;
    int c0 = (i0 < NCB) ? cnt[i0] : 0;
    int c1 = (i1 < NCB) ? cnt[i1] : 0;
    sc[tid] = c0 + c1;
    __syncthreads();
    for (int off = 1; off < 256; off <<= 1) {
        int v = (tid >= off) ? sc[tid - off] : 0;
        __syncthreads();
        sc[tid] += v;
        __syncthreads();
    }
    int run = tid ? sc[tid - 1] : 0;
    if (i0 < NCB) {
        base[i0] = run; cur[i0] = run;
        gposs[i0] = atomicAdd(&gcur[i0], c0);
        run += c0;
    }
    if (i1 < NCB) {
        base[i1] = run; cur[i1] = run;
        gposs[i1] = atomicAdd(&gcur[i1], c1);
        run += c1;
    }
    __syncthreads();
    for (int i = e0 / 4 + tid; i < e1 / 4; i += 256) {
        int4 d = ((const int4*)edst)[i];
        int4 s = ((const int4*)esrc)[i];
        lpk[atomicAdd(&cur[d.x >> 7], 1)] = s.x | ((d.x & 127) << 17);
        lpk[atomicAdd(&cur[d.y >> 7], 1)] = s.y | ((d.y & 127) << 17);
        lpk[atomicAdd(&cur[d.z >> 7], 1)] = s.z | ((d.z & 127) << 17);
        lpk[atomicAdd(&cur[d.w >> 7], 1)] = s.w | ((d.w & 127) << 17);
    }
    __syncthreads();
    int wid = tid >> 6, lane = tid & 63;
    for (int c = wid; c < NCB; c += 4) {
        int n = cnt[c], gb = gposs[c], lb = base[c];
        for (int i = lane; i < n; i += 64) pk_g[gb + i] = lpk[lb + i];
    }
}

// ---- pass B: per coarse bucket (128 nodes), build fine CSR + offsets in LDS ----
__global__ void partb_k(const int* __restrict__ pk_g, const int* __restrict__ cbase,
                        int* __restrict__ offsets, int* __restrict__ csr) {
    __shared__ int cnt[128];
    __shared__ int sc[256];
    __shared__ int lpk[CAP_B];
    int b = blockIdx.x, tid = threadIdx.x;
    int ebeg = cbase[b], eend = cbase[b + 1], n = eend - ebeg;
    int nbeg = b * 128;
    int ncnt = min(128, NN - nbeg);
    if (tid < 128) cnt[tid] = 0;
    __syncthreads();
    bool fits = (n <= CAP_B);
    if (fits) {
        for (int i = tid; i < n; i += 256) {
            int p = pk_g[ebeg + i];
            lpk[i] = p;
            atomicAdd(&cnt[p >> 17], 1);
        }
    } else {
        for (int i = tid; i < n; i += 256) atomicAdd(&cnt[pk_g[ebeg + i] >> 17], 1);
    }
    __syncthreads();
    int c0 = (tid < 128) ? cnt[tid] : 0;
    sc[tid] = c0;
    __syncthreads();
    for (int off = 1; off < 128; off <<= 1) {
        int v = (tid >= off && tid < 128) ? sc[tid - off] : 0;
        __syncthreads();
        if (tid < 128) sc[tid] += v;
        __syncthreads();
    }
    int excl = (tid < 128) ? sc[tid] - c0 : 0;
    if (tid < ncnt) offsets[nbeg + tid] = ebeg + excl;
    if (b == NCB - 1 && tid == 0) offsets[NN] = eend;
    __syncthreads();
    if (tid < 128) cnt[tid] = ebeg + excl;
    __syncthreads();
    if (fits) {
        for (int i = tid; i < n; i += 256) {
            int p = lpk[i];
            csr[atomicAdd(&cnt[p >> 17], 1)] = p & 0x1FFFF;
        }
    } else {
        for (int i = tid; i < n; i += 256) {
            int p = pk_g[ebeg + i];
            csr[atomicAdd(&cnt[p >> 17], 1)] = p & 0x1FFFF;
        }
    }
}

// ---- fused per-node GAT aggregation: ONE NODE PER WAVE, single pass (no max) ----
// Gather loop unrolled x16 for deep memory-level parallelism.
template <int F, bool RELU>
__global__ void node_agg_k(const int* __restrict__ off, const int* __restrict__ csr,
                           const float* __restrict__ as_, const float* __restrict__ ad_,
                           const unsigned* __restrict__ Hb2,
                           const float* __restrict__ b, float* __restrict__ O) {
    int lane = threadIdx.x & 63;
    int node = blockIdx.x * (blockDim.x >> 6) + (threadIdx.x >> 6);
    if (node >= NN) return;
    int beg = off[node], end = off[node + 1];
    float adn = ad_[node];
    float vself = as_[node] + adn;
    vself = vself > 0.f ? vself : 0.2f * vself;
    float eself = __expf(vself);
    float lsum = 0.f;

    if constexpr (F == 128) {
        unsigned hbs = Hb2[(size_t)node * 64 + lane];
        float accx = eself * bflo(hbs);
        float accy = eself * bfhi(hbs);
        for (int i0 = beg; i0 < end; i0 += 64) {
            int idx = i0 + lane;
            bool ok = idx < end;
            int s = ok ? csr[idx] : 0;
            float v = as_[s] + adn;
            v = v > 0.f ? v : 0.2f * v;
            float ee = ok ? __expf(v) : 0.f;
            lsum += ee;
            int rem = min(end - i0, 64);
            int j = 0;
            for (; j + 16 <= rem; j += 16) {
#pragma unroll
                for (int k = 0; k < 16; ++k) {
                    int s2 = __builtin_amdgcn_readlane(s, j + k);
                    float ee2 = rdlane_f(ee, j + k);
                    unsigned hb = (Hb2 + (size_t)s2 * 64)[lane];
                    accx += ee2 * bflo(hb);
                    accy += ee2 * bfhi(hb);
                }
            }
            for (; j + 4 <= rem; j += 4) {
#pragma unroll
                for (int k = 0; k < 4; ++k) {
                    int s2 = __builtin_amdgcn_readlane(s, j + k);
                    float ee2 = rdlane_f(ee, j + k);
                    unsigned hb = (Hb2 + (size_t)s2 * 64)[lane];
                    accx += ee2 * bflo(hb);
                    accy += ee2 * bfhi(hb);
                }
            }
            for (; j < rem; ++j) {
                int s2 = __builtin_amdgcn_readlane(s, j);
                float ee2 = rdlane_f(ee, j);
                unsigned hb = (Hb2 + (size_t)s2 * 64)[lane];
                accx += ee2 * bflo(hb);
                accy += ee2 * bfhi(hb);
            }
        }
#pragma unroll
        for (int o = 32; o; o >>= 1) lsum += __shfl_xor(lsum, o);
        float inv = 1.f / (lsum + eself + 1e-16f);
        float2 bb = ((const float2*)b)[lane];
        float ox = accx * inv + bb.x;
        float oy = accy * inv + bb.y;
        if (RELU) { ox = fmaxf(ox, 0.f); oy = fmaxf(oy, 0.f); }
        ((float2*)O)[(size_t)node * 64 + lane] = make_float2(ox, oy);
    } else if constexpr (F == 64) {
        const unsigned short* Hs = (const unsigned short*)Hb2;
        float acc = eself * bflo((unsigned)Hs[(size_t)node * 64 + lane]);
        for (int i0 = beg; i0 < end; i0 += 64) {
            int idx = i0 + lane;
            bool ok = idx < end;
            int s = ok ? csr[idx] : 0;
            float v = as_[s] + adn;
            v = v > 0.f ? v : 0.2f * v;
            float ee = ok ? __expf(v) : 0.f;
            lsum += ee;
            int rem = min(end - i0, 64);
            int j = 0;
            for (; j + 16 <= rem; j += 16) {
#pragma unroll
                for (int k = 0; k < 16; ++k) {
                    int s2 = __builtin_amdgcn_readlane(s, j + k);
                    float ee2 = rdlane_f(ee, j + k);
                    acc += ee2 * bflo((unsigned)(Hs + (size_t)s2 * 64)[lane]);
                }
            }
            for (; j + 4 <= rem; j += 4) {
#pragma unroll
                for (int k = 0; k < 4; ++k) {
                    int s2 = __builtin_amdgcn_readlane(s, j + k);
                    float ee2 = rdlane_f(ee, j + k);
                    acc += ee2 * bflo((unsigned)(Hs + (size_t)s2 * 64)[lane]);
                }
            }
            for (; j < rem; ++j) {
                int s2 = __builtin_amdgcn_readlane(s, j);
                float ee2 = rdlane_f(ee, j);
                acc += ee2 * bflo((unsigned)(Hs + (size_t)s2 * 64)[lane]);
            }
        }
#pragma unroll
        for (int o = 32; o; o >>= 1) lsum += __shfl_xor(lsum, o);
        float inv = 1.f / (lsum + eself + 1e-16f);
        float ox = acc * inv + b[lane];
        if (RELU) ox = fmaxf(ox, 0.f);
        O[(size_t)node * 64 + lane] = ox;
    } else {  // F == 32
        const int GRP = 16, EPG = 4, U = 4;
        int sg = lane / GRP;
        int cl = lane % GRP;
        unsigned hbs = Hb2[(size_t)node * GRP + cl];
        float accx = (sg == 0) ? eself * bflo(hbs) : 0.f;
        float accy = (sg == 0) ? eself * bfhi(hbs) : 0.f;
        for (int i0 = beg; i0 < end; i0 += 64) {
            int idx = i0 + lane;
            bool ok = idx < end;
            int s = ok ? csr[idx] : 0;
            float v = as_[s] + adn;
            v = v > 0.f ? v : 0.2f * v;
            float ee = ok ? __expf(v) : 0.f;
            lsum += ee;
            int rem = min(end - i0, 64);
            int nj = (rem + EPG - 1) / EPG;
            nj = (nj + U - 1) & ~(U - 1);
            for (int j = 0; j < nj; j += U) {
#pragma unroll
                for (int k = 0; k < U; ++k) {
                    int pos = (j + k) * EPG + sg;
                    int s2 = __shfl(s, pos);
                    float ee2 = __shfl(ee, pos);
                    unsigned hb = Hb2[(size_t)s2 * GRP + cl];
                    accx += ee2 * bflo(hb);
                    accy += ee2 * bfhi(hb);
                }
            }
        }
#pragma unroll
        for (int o = 32; o; o >>= 1) lsum += __shfl_xor(lsum, o);
        float sum = lsum + eself;
#pragma unroll
        for (int o = 32; o >= GRP; o >>= 1) {
            accx += __shfl_xor(accx, o);
            accy += __shfl_xor(accy, o);
        }
        if (sg == 0) {
            float inv = 1.f / (sum + 1e-16f);
            float2 bb = ((const float2*)b)[cl];
            float ox = accx * inv + bb.x;
            float oy = accy * inv + bb.y;
            if (RELU) { ox = fmaxf(ox, 0.f); oy = fmaxf(oy, 0.f); }
            ((float2*)O)[(size_t)node * GRP + cl] = make_float2(ox, oy);
        }
    }
}

// ---- global_add_pool ----
__global__ void pool_k(const float* __restrict__ O, const int* __restrict__ batch,
                       float* __restrict__ g, int nodes_per_block) {
    __shared__ float acc[NG * 128];
    int c = threadIdx.x;
    for (int i = 0; i < NG; ++i) acc[i * 128 + c] = 0.f;
    int start = blockIdx.x * nodes_per_block;
    int end = min(start + nodes_per_block, NN);
    int gmin = NG - 1, gmax = 0;
    for (int nd = start; nd < end; ++nd) {
        int gg = batch[nd];
        gmin = min(gmin, gg);
        gmax = max(gmax, gg);
        acc[gg * 128 + c] += O[(size_t)nd * 128 + c];
    }
    for (int i = gmin; i <= gmax; ++i) atomicAdd(g + i * 128 + c, acc[i * 128 + c]);
}

// ---- head ----
__global__ void head_k(const float* __restrict__ g, const float* __restrict__ l1W,
                       const float* __restrict__ l1b, const float* __restrict__ l2W,
                       const float* __restrict__ l2b, float* __restrict__ out) {
    __shared__ float h1[NG * 32];
    __shared__ float o[NG * 10];
    int tid = threadIdx.x;
    for (int idx = tid; idx < NG * 32; idx += 256) {
        int r = idx / 32, c = idx % 32;
        float acc = l1b[c];
        for (int k = 0; k < 128; ++k) acc += g[r * 128 + k] * l1W[k * 32 + c];
        h1[idx] = fmaxf(acc, 0.f);
    }
    __syncthreads();
    for (int idx = tid; idx < NG * 10; idx += 256) {
        int r = idx / 10, c = idx % 10;
        float acc = l2b[c];
        for (int k = 0; k < 32; ++k) acc += h1[r * 32 + k] * l2W[k * 10 + c];
        o[idx] = acc;
    }
    __syncthreads();
    if (tid < 10) {
        float mx = -1e30f;
        for (int r = 0; r < NG; ++r) mx = fmaxf(mx, o[r * 10 + tid]);
        float sum = 0.f;
        for (int r = 0; r < NG; ++r) sum += __expf(o[r * 10 + tid] - mx);
        float lse = mx + logf(sum);
        for (int r = 0; r < NG; ++r) out[r * 10 + tid] = o[r * 10 + tid] - lse;
    }
}

extern "C" void kernel_launch(void* const* d_in, const int* in_sizes, int n_in,
                              void* d_out, int out_size, void* d_ws, size_t ws_size,
                              hipStream_t stream) {
    const float* x   = (const float*)d_in[0];
    const int* ei    = (const int*)d_in[1];
    const int* batch = (const int*)d_in[2];
    const float* W1 = (const float*)d_in[3];
    const float* as1 = (const float*)d_in[4];
    const float* ad1 = (const float*)d_in[5];
    const float* b1 = (const float*)d_in[6];
    const float* W2 = (const float*)d_in[7];
    const float* as2 = (const float*)d_in[8];
    const float* ad2 = (const float*)d_in[9];
    const float* b2 = (const float*)d_in[10];
    const float* W3 = (const float*)d_in[11];
    const float* as3 = (const float*)d_in[12];
    const float* ad3 = (const float*)d_in[13];
    const float* b3 = (const float*)d_in[14];
    const float* l1W = (const float*)d_in[15];
    const float* l1b = (const float*)d_in[16];
    const float* l2W = (const float*)d_in[17];
    const float* l2b = (const float*)d_in[18];
    float* out = (float*)d_out;

    const int* esrc = ei;
    const int* edst = ei + NE;

    char* ws = (char*)d_ws;
    float* B0 = (float*)ws;                            // NN*128 f32
    float* B1 = B0 + (size_t)NN * 128;                 // NN*64 f32
    unsigned* Hb = (unsigned*)(B1 + (size_t)NN * 64);  // NN*64 uints (NN*128 bf16)
    float* as_ = (float*)(Hb + (size_t)NN * 64);       // NN
    float* ad_ = as_ + NN;                             // NN
    int* gcount = (int*)(ad_ + NN);                    // NCB   \ one memset
    float* g    = (float*)(gcount + NCB);              // NG*128/
    int* cbase  = (int*)(g + NG * 128);                // NCB+1
    int* gcur   = cbase + NCB + 1;                     // NCB
    int* offsets = gcur + NCB + 2;                     // NN+1
    int* csr    = offsets + NN + 1;                    // NE
    int* pk     = csr + NE;                            // NE staging
    const int GEMM_BLOCKS = (NN + 31) / 32;            // 1563

    // zero gcount + g in one shot (contiguous)
    hipMemsetAsync(gcount, 0, (NCB + NG * 128) * 4, stream);

    // layer-1 GEMM+logits co-dispatched with coarse histogram
    gemm_att_k<128, 32, true><<<GEMM_BLOCKS + HB, 256, 0, stream>>>(
        x, W1, as1, ad1, Hb, as_, ad_, GEMM_BLOCKS, edst, gcount);
    cscan_k<<<1, 256, 0, stream>>>(gcount, cbase, gcur);
    parta_k<<<(NE + EPB_A - 1) / EPB_A, 256, 0, stream>>>(esrc, edst, gcur, pk);
    partb_k<<<NCB, 256, 0, stream>>>(pk, cbase, offsets, csr);
    node_agg_k<32, true><<<(NN + 3) / 4, 256, 0, stream>>>(offsets, csr, as_, ad_, Hb, b1, B0);

    gemm_att_k<32, 64, false><<<GEMM_BLOCKS, 256, 0, stream>>>(
        B0, W2, as2, ad2, Hb, as_, ad_, GEMM_BLOCKS, nullptr, nullptr);
    node_agg_k<64, true><<<(NN + 3) / 4, 256, 0, stream>>>(offsets, csr, as_, ad_, Hb, b2, B1);

    gemm_att_k<64, 128, false><<<GEMM_BLOCKS, 256, 0, stream>>>(
        B1, W3, as3, ad3, Hb, as_, ad_, GEMM_BLOCKS, nullptr, nullptr);
    node_agg_k<128, false><<<(NN + 3) / 4, 256, 0, stream>>>(offsets, csr, as_, ad_, Hb, b3, B0);

    pool_k<<<(NN + 127) / 128, 128, 0, stream>>>(B0, batch, g, 128);
    head_k<<<1, 256, 0, stream>>>(g, l1W, l1b, l2W, l2b, out);
}

// Round 12
// 289.028 us; speedup vs baseline: 1.0813x; 1.0292x over previous
//
#include <hip/hip_runtime.h>
#include <cstdint>
#include <cstddef>

#define NN 50000
#define NE 1600000
#define NG 64
#define NCB 391          // coarse buckets: dst>>7, 128 nodes each
#define HB 98            // histogram blocks co-dispatched with gemm1
#define EPB_A 8192       // edges per parta block
#define CAP_B 8192       // LDS edge capacity in partb

// ---- bf16 helpers ----
__device__ __forceinline__ float bflo(unsigned u) { return __uint_as_float(u << 16); }
__device__ __forceinline__ float bfhi(unsigned u) { return __uint_as_float(u & 0xffff0000u); }
__device__ __forceinline__ unsigned f2bf(float f) {  // RTNE, returns low 16 bits
    unsigned u = __float_as_uint(f);
    return (u + 0x7fffu + ((u >> 16) & 1u)) >> 16;
}
__device__ __forceinline__ float rdlane_f(float v, int l) {
    return __uint_as_float((unsigned)__builtin_amdgcn_readlane((int)__float_as_uint(v), l));
}

// ---- fused tiled GEMM + attention logits (+ optional co-dispatched coarse hist) ----
template <int FIN, int FOUT, bool HIST>
__global__ void gemm_att_k(const float* __restrict__ A, const float* __restrict__ W,
                           const float* __restrict__ a_src, const float* __restrict__ a_dst,
                           unsigned* __restrict__ Hb, float* __restrict__ as_,
                           float* __restrict__ ad_, int gemmBlocks,
                           const int* __restrict__ edst, int* __restrict__ gcount) {
    __shared__ float Wl[FIN * FOUT];
    __shared__ float Al[32 * FIN];
    __shared__ int hh[NCB];
    int tid = threadIdx.x;
    if (HIST && blockIdx.x >= gemmBlocks) {
        int bid = blockIdx.x - gemmBlocks;
        for (int i = tid; i < NCB; i += 256) hh[i] = 0;
        __syncthreads();
        const int total4 = NE / 4;
        for (int i = bid * 256 + tid; i < total4; i += HB * 256) {
            int4 d = ((const int4*)edst)[i];
            atomicAdd(&hh[d.x >> 7], 1);
            atomicAdd(&hh[d.y >> 7], 1);
            atomicAdd(&hh[d.z >> 7], 1);
            atomicAdd(&hh[d.w >> 7], 1);
        }
        __syncthreads();
        for (int i = tid; i < NCB; i += 256)
            if (hh[i]) atomicAdd(&gcount[i], hh[i]);
        return;
    }
    const int RPB = 32;
    const int CP = FOUT / 2;
    const int CLANES = 256 / CP;
    const int RL = RPB / CLANES;
    for (int i = tid; i < (FIN * FOUT) / 4; i += 256)
        ((float4*)Wl)[i] = ((const float4*)W)[i];
    int rowbase = blockIdx.x * RPB;
    int nrows = min(RPB, NN - rowbase);
    int nel4 = (nrows * FIN) / 4;
    const float4* Asrc = (const float4*)(A + (size_t)rowbase * FIN);
    for (int i = tid; i < nel4; i += 256) ((float4*)Al)[i] = Asrc[i];
    __syncthreads();
    int c2 = tid % CP;
    int rb = tid / CP;
    float acc0[RL], acc1[RL];
#pragma unroll
    for (int r = 0; r < RL; ++r) { acc0[r] = 0.f; acc1[r] = 0.f; }
#pragma unroll 4
    for (int k = 0; k < FIN; ++k) {
        float w0 = Wl[k * FOUT + 2 * c2];
        float w1 = Wl[k * FOUT + 2 * c2 + 1];
#pragma unroll
        for (int r = 0; r < RL; ++r) {
            float a = Al[(rb + r * CLANES) * FIN + k];
            acc0[r] += a * w0;
            acc1[r] += a * w1;
        }
    }
    float2 asrc2 = ((const float2*)a_src)[c2];
    float2 adst2 = ((const float2*)a_dst)[c2];
#pragma unroll
    for (int r = 0; r < RL; ++r) {
        int row = rowbase + rb + r * CLANES;
        float p1 = acc0[r] * asrc2.x + acc1[r] * asrc2.y;
        float p2 = acc0[r] * adst2.x + acc1[r] * adst2.y;
#pragma unroll
        for (int o = CP >> 1; o; o >>= 1) {
            p1 += __shfl_xor(p1, o, CP);
            p2 += __shfl_xor(p2, o, CP);
        }
        if (row < NN) {
            Hb[(size_t)row * CP + c2] = f2bf(acc0[r]) | (f2bf(acc1[r]) << 16);
            if (c2 == 0) { as_[row] = p1; ad_[row] = p2; }
        }
    }
}

// ---- scan coarse counts -> cbase; init gcur (2 entries per thread) ----
__global__ void cscan_k(const int* __restrict__ gcount, int* __restrict__ cbase,
                        int* __restrict__ gcur) {
    __shared__ int part[256];
    int tid = threadIdx.x;
    int i0 = 2 * tid, i1 = 2 * tid + 1;
    int v0 = (i0 < NCB) ? gcount[i0] : 0;
    int v1 = (i1 < NCB) ? gcount[i1] : 0;
    part[tid] = v0 + v1;
    __syncthreads();
    for (int off = 1; off < 256; off <<= 1) {
        int v = (tid >= off) ? part[tid - off] : 0;
        __syncthreads();
        part[tid] += v;
        __syncthreads();
    }
    int run = tid ? part[tid - 1] : 0;
    if (i0 < NCB) { cbase[i0] = run; gcur[i0] = run; run += v0; }
    if (i1 < NCB) { cbase[i1] = run; gcur[i1] = run; run += v1; }
    if (tid == 255) cbase[NCB] = part[255];
}

// ---- pass A: partition edges into coarse buckets with dense LDS-staged flushes ----
__global__ void parta_k(const int* __restrict__ esrc, const int* __restrict__ edst,
                        int* __restrict__ gcur, int* __restrict__ pk_g) {
    __shared__ int cnt[NCB];
    __shared__ int base[NCB];
    __shared__ int cur[NCB];
    __shared__ int gposs[NCB];
    __shared__ int sc[256];
    __shared__ int lpk[EPB_A];
    int tid = threadIdx.x;
    int e0 = blockIdx.x * EPB_A;
    int e1 = min(e0 + EPB_A, NE);
    for (int i = tid; i < NCB; i += 256) cnt[i] = 0;
    __syncthreads();
    for (int i = e0 / 4 + tid; i < e1 / 4; i += 256) {
        int4 d = ((const int4*)edst)[i];
        atomicAdd(&cnt[d.x >> 7], 1);
        atomicAdd(&cnt[d.y >> 7], 1);
        atomicAdd(&cnt[d.z >> 7], 1);
        atomicAdd(&cnt[d.w >> 7], 1);
    }
    __syncthreads();
    int i0 = 2 * tid, i1 = 2 * tid + 1;
    int c0 = (i0 < NCB) ? cnt[i0] : 0;
    int c1 = (i1 < NCB) ? cnt[i1] : 0;
    sc[tid] = c0 + c1;
    __syncthreads();
    for (int off = 1; off < 256; off <<= 1) {
        int v = (tid >= off) ? sc[tid - off] : 0;
        __syncthreads();
        sc[tid] += v;
        __syncthreads();
    }
    int run = tid ? sc[tid - 1] : 0;
    if (i0 < NCB) {
        base[i0] = run; cur[i0] = run;
        gposs[i0] = atomicAdd(&gcur[i0], c0);
        run += c0;
    }
    if (i1 < NCB) {
        base[i1] = run; cur[i1] = run;
        gposs[i1] = atomicAdd(&gcur[i1], c1);
        run += c1;
    }
    __syncthreads();
    for (int i = e0 / 4 + tid; i < e1 / 4; i += 256) {
        int4 d = ((const int4*)edst)[i];
        int4 s = ((const int4*)esrc)[i];
        lpk[atomicAdd(&cur[d.x >> 7], 1)] = s.x | ((d.x & 127) << 17);
        lpk[atomicAdd(&cur[d.y >> 7], 1)] = s.y | ((d.y & 127) << 17);
        lpk[atomicAdd(&cur[d.z >> 7], 1)] = s.z | ((d.z & 127) << 17);
        lpk[atomicAdd(&cur[d.w >> 7], 1)] = s.w | ((d.w & 127) << 17);
    }
    __syncthreads();
    int wid = tid >> 6, lane = tid & 63;
    for (int c = wid; c < NCB; c += 4) {
        int n = cnt[c], gb = gposs[c], lb = base[c];
        for (int i = lane; i < n; i += 64) pk_g[gb + i] = lpk[lb + i];
    }
}

// ---- pass B: per coarse bucket (128 nodes), build fine CSR + offsets in LDS ----
__global__ void partb_k(const int* __restrict__ pk_g, const int* __restrict__ cbase,
                        int* __restrict__ offsets, int* __restrict__ csr) {
    __shared__ int cnt[128];
    __shared__ int sc[256];
    __shared__ int lpk[CAP_B];
    int b = blockIdx.x, tid = threadIdx.x;
    int ebeg = cbase[b], eend = cbase[b + 1], n = eend - ebeg;
    int nbeg = b * 128;
    int ncnt = min(128, NN - nbeg);
    if (tid < 128) cnt[tid] = 0;
    __syncthreads();
    bool fits = (n <= CAP_B);
    if (fits) {
        for (int i = tid; i < n; i += 256) {
            int p = pk_g[ebeg + i];
            lpk[i] = p;
            atomicAdd(&cnt[p >> 17], 1);
        }
    } else {
        for (int i = tid; i < n; i += 256) atomicAdd(&cnt[pk_g[ebeg + i] >> 17], 1);
    }
    __syncthreads();
    int c0 = (tid < 128) ? cnt[tid] : 0;
    sc[tid] = c0;
    __syncthreads();
    for (int off = 1; off < 128; off <<= 1) {
        int v = (tid >= off && tid < 128) ? sc[tid - off] : 0;
        __syncthreads();
        if (tid < 128) sc[tid] += v;
        __syncthreads();
    }
    int excl = (tid < 128) ? sc[tid] - c0 : 0;
    if (tid < ncnt) offsets[nbeg + tid] = ebeg + excl;
    if (b == NCB - 1 && tid == 0) offsets[NN] = eend;
    __syncthreads();
    if (tid < 128) cnt[tid] = ebeg + excl;
    __syncthreads();
    if (fits) {
        for (int i = tid; i < n; i += 256) {
            int p = lpk[i];
            csr[atomicAdd(&cnt[p >> 17], 1)] = p & 0x1FFFF;
        }
    } else {
        for (int i = tid; i < n; i += 256) {
            int p = pk_g[ebeg + i];
            csr[atomicAdd(&cnt[p >> 17], 1)] = p & 0x1FFFF;
        }
    }
}

// ---- fused per-node GAT aggregation: ONE NODE PER 64-THREAD BLOCK (one wave) ----
// F==128: wave-per-edge, readlane+saddr gather, unroll x16.
// F==64 : 2 edge-subgroups of 32 lanes, uint loads, shfl broadcast, unroll x4.
// F==32 : 4 edge-subgroups of 16 lanes, uint loads, shfl broadcast, unroll x4.
template <int F, bool RELU>
__global__ void node_agg_k(const int* __restrict__ off, const int* __restrict__ csr,
                           const float* __restrict__ as_, const float* __restrict__ ad_,
                           const unsigned* __restrict__ Hb2,
                           const float* __restrict__ b, float* __restrict__ O) {
    int lane = threadIdx.x;
    int node = blockIdx.x;
    int beg = off[node], end = off[node + 1];
    float adn = ad_[node];
    float vself = as_[node] + adn;
    vself = vself > 0.f ? vself : 0.2f * vself;
    float eself = __expf(vself);
    float lsum = 0.f;

    if constexpr (F == 128) {
        unsigned hbs = Hb2[(size_t)node * 64 + lane];
        float accx = eself * bflo(hbs);
        float accy = eself * bfhi(hbs);
        for (int i0 = beg; i0 < end; i0 += 64) {
            int idx = i0 + lane;
            bool ok = idx < end;
            int s = ok ? csr[idx] : 0;
            float v = as_[s] + adn;
            v = v > 0.f ? v : 0.2f * v;
            float ee = ok ? __expf(v) : 0.f;
            lsum += ee;
            int rem = min(end - i0, 64);
            int j = 0;
            for (; j + 16 <= rem; j += 16) {
#pragma unroll
                for (int k = 0; k < 16; ++k) {
                    int s2 = __builtin_amdgcn_readlane(s, j + k);
                    float ee2 = rdlane_f(ee, j + k);
                    unsigned hb = (Hb2 + (size_t)s2 * 64)[lane];
                    accx += ee2 * bflo(hb);
                    accy += ee2 * bfhi(hb);
                }
            }
            for (; j + 4 <= rem; j += 4) {
#pragma unroll
                for (int k = 0; k < 4; ++k) {
                    int s2 = __builtin_amdgcn_readlane(s, j + k);
                    float ee2 = rdlane_f(ee, j + k);
                    unsigned hb = (Hb2 + (size_t)s2 * 64)[lane];
                    accx += ee2 * bflo(hb);
                    accy += ee2 * bfhi(hb);
                }
            }
            for (; j < rem; ++j) {
                int s2 = __builtin_amdgcn_readlane(s, j);
                float ee2 = rdlane_f(ee, j);
                unsigned hb = (Hb2 + (size_t)s2 * 64)[lane];
                accx += ee2 * bflo(hb);
                accy += ee2 * bfhi(hb);
            }
        }
#pragma unroll
        for (int o = 32; o; o >>= 1) lsum += __shfl_xor(lsum, o);
        float inv = 1.f / (lsum + eself + 1e-16f);
        float2 bb = ((const float2*)b)[lane];
        float ox = accx * inv + bb.x;
        float oy = accy * inv + bb.y;
        if (RELU) { ox = fmaxf(ox, 0.f); oy = fmaxf(oy, 0.f); }
        ((float2*)O)[(size_t)node * 64 + lane] = make_float2(ox, oy);
    } else if constexpr (F == 64) {
        // 2 edge-subgroups of 32 lanes, each lane owns a uint (2 bf16 cols)
        int sg = lane >> 5;       // 0/1
        int cl = lane & 31;       // column-pair lane
        unsigned hbs = Hb2[(size_t)node * 32 + cl];
        float accx = (sg == 0) ? eself * bflo(hbs) : 0.f;
        float accy = (sg == 0) ? eself * bfhi(hbs) : 0.f;
        for (int i0 = beg; i0 < end; i0 += 64) {
            int idx = i0 + lane;
            bool ok = idx < end;
            int s = ok ? csr[idx] : 0;
            float v = as_[s] + adn;
            v = v > 0.f ? v : 0.2f * v;
            float ee = ok ? __expf(v) : 0.f;   // padded lanes contribute 0
            lsum += ee;
            int rem = min(end - i0, 64);
            int nj = (rem + 1) >> 1;
            nj = (nj + 3) & ~3;                // pad to x4; nj<=32 so pos<=63
            for (int j = 0; j < nj; j += 4) {
#pragma unroll
                for (int k = 0; k < 4; ++k) {
                    int pos = (j + k) * 2 + sg;
                    int s2 = __shfl(s, pos);
                    float ee2 = __shfl(ee, pos);
                    unsigned hb = Hb2[(size_t)s2 * 32 + cl];
                    accx += ee2 * bflo(hb);
                    accy += ee2 * bfhi(hb);
                }
            }
        }
#pragma unroll
        for (int o = 32; o; o >>= 1) lsum += __shfl_xor(lsum, o);
        float sum = lsum + eself;
        accx += __shfl_xor(accx, 32);
        accy += __shfl_xor(accy, 32);
        if (sg == 0) {
            float inv = 1.f / (sum + 1e-16f);
            float2 bb = ((const float2*)b)[cl];
            float ox = accx * inv + bb.x;
            float oy = accy * inv + bb.y;
            if (RELU) { ox = fmaxf(ox, 0.f); oy = fmaxf(oy, 0.f); }
            ((float2*)O)[(size_t)node * 32 + cl] = make_float2(ox, oy);
        }
    } else {  // F == 32
        const int GRP = 16, EPG = 4, U = 4;
        int sg = lane / GRP;
        int cl = lane % GRP;
        unsigned hbs = Hb2[(size_t)node * GRP + cl];
        float accx = (sg == 0) ? eself * bflo(hbs) : 0.f;
        float accy = (sg == 0) ? eself * bfhi(hbs) : 0.f;
        for (int i0 = beg; i0 < end; i0 += 64) {
            int idx = i0 + lane;
            bool ok = idx < end;
            int s = ok ? csr[idx] : 0;
            float v = as_[s] + adn;
            v = v > 0.f ? v : 0.2f * v;
            float ee = ok ? __expf(v) : 0.f;
            lsum += ee;
            int rem = min(end - i0, 64);
            int nj = (rem + EPG - 1) / EPG;
            nj = (nj + U - 1) & ~(U - 1);
            for (int j = 0; j < nj; j += U) {
#pragma unroll
                for (int k = 0; k < U; ++k) {
                    int pos = (j + k) * EPG + sg;
                    int s2 = __shfl(s, pos);
                    float ee2 = __shfl(ee, pos);
                    unsigned hb = Hb2[(size_t)s2 * GRP + cl];
                    accx += ee2 * bflo(hb);
                    accy += ee2 * bfhi(hb);
                }
            }
        }
#pragma unroll
        for (int o = 32; o; o >>= 1) lsum += __shfl_xor(lsum, o);
        float sum = lsum + eself;
#pragma unroll
        for (int o = 32; o >= GRP; o >>= 1) {
            accx += __shfl_xor(accx, o);
            accy += __shfl_xor(accy, o);
        }
        if (sg == 0) {
            float inv = 1.f / (sum + 1e-16f);
            float2 bb = ((const float2*)b)[cl];
            float ox = accx * inv + bb.x;
            float oy = accy * inv + bb.y;
            if (RELU) { ox = fmaxf(ox, 0.f); oy = fmaxf(oy, 0.f); }
            ((float2*)O)[(size_t)node * GRP + cl] = make_float2(ox, oy);
        }
    }
}

// ---- global_add_pool ----
__global__ void pool_k(const float* __restrict__ O, const int* __restrict__ batch,
                       float* __restrict__ g, int nodes_per_block) {
    __shared__ float acc[NG * 128];
    int c = threadIdx.x;
    for (int i = 0; i < NG; ++i) acc[i * 128 + c] = 0.f;
    int start = blockIdx.x * nodes_per_block;
    int end = min(start + nodes_per_block, NN);
    int gmin = NG - 1, gmax = 0;
    for (int nd = start; nd < end; ++nd) {
        int gg = batch[nd];
        gmin = min(gmin, gg);
        gmax = max(gmax, gg);
        acc[gg * 128 + c] += O[(size_t)nd * 128 + c];
    }
    for (int i = gmin; i <= gmax; ++i) atomicAdd(g + i * 128 + c, acc[i * 128 + c]);
}

// ---- head ----
__global__ void head_k(const float* __restrict__ g, const float* __restrict__ l1W,
                       const float* __restrict__ l1b, const float* __restrict__ l2W,
                       const float* __restrict__ l2b, float* __restrict__ out) {
    __shared__ float h1[NG * 32];
    __shared__ float o[NG * 10];
    int tid = threadIdx.x;
    for (int idx = tid; idx < NG * 32; idx += 256) {
        int r = idx / 32, c = idx % 32;
        float acc = l1b[c];
        for (int k = 0; k < 128; ++k) acc += g[r * 128 + k] * l1W[k * 32 + c];
        h1[idx] = fmaxf(acc, 0.f);
    }
    __syncthreads();
    for (int idx = tid; idx < NG * 10; idx += 256) {
        int r = idx / 10, c = idx % 10;
        float acc = l2b[c];
        for (int k = 0; k < 32; ++k) acc += h1[r * 32 + k] * l2W[k * 10 + c];
        o[idx] = acc;
    }
    __syncthreads();
    if (tid < 10) {
        float mx = -1e30f;
        for (int r = 0; r < NG; ++r) mx = fmaxf(mx, o[r * 10 + tid]);
        float sum = 0.f;
        for (int r = 0; r < NG; ++r) sum += __expf(o[r * 10 + tid] - mx);
        float lse = mx + logf(sum);
        for (int r = 0; r < NG; ++r) out[r * 10 + tid] = o[r * 10 + tid] - lse;
    }
}

extern "C" void kernel_launch(void* const* d_in, const int* in_sizes, int n_in,
                              void* d_out, int out_size, void* d_ws, size_t ws_size,
                              hipStream_t stream) {
    const float* x   = (const float*)d_in[0];
    const int* ei    = (const int*)d_in[1];
    const int* batch = (const int*)d_in[2];
    const float* W1 = (const float*)d_in[3];
    const float* as1 = (const float*)d_in[4];
    const float* ad1 = (const float*)d_in[5];
    const float* b1 = (const float*)d_in[6];
    const float* W2 = (const float*)d_in[7];
    const float* as2 = (const float*)d_in[8];
    const float* ad2 = (const float*)d_in[9];
    const float* b2 = (const float*)d_in[10];
    const float* W3 = (const float*)d_in[11];
    const float* as3 = (const float*)d_in[12];
    const float* ad3 = (const float*)d_in[13];
    const float* b3 = (const float*)d_in[14];
    const float* l1W = (const float*)d_in[15];
    const float* l1b = (const float*)d_in[16];
    const float* l2W = (const float*)d_in[17];
    const float* l2b = (const float*)d_in[18];
    float* out = (float*)d_out;

    const int* esrc = ei;
    const int* edst = ei + NE;

    char* ws = (char*)d_ws;
    float* B0 = (float*)ws;                            // NN*128 f32
    float* B1 = B0 + (size_t)NN * 128;                 // NN*64 f32
    unsigned* Hb = (unsigned*)(B1 + (size_t)NN * 64);  // NN*64 uints (NN*128 bf16)
    float* as_ = (float*)(Hb + (size_t)NN * 64);       // NN
    float* ad_ = as_ + NN;                             // NN
    int* gcount = (int*)(ad_ + NN);                    // NCB   \ one memset
    float* g    = (float*)(gcount + NCB);              // NG*128/
    int* cbase  = (int*)(g + NG * 128);                // NCB+1
    int* gcur   = cbase + NCB + 1;                     // NCB
    int* offsets = gcur + NCB + 2;                     // NN+1
    int* csr    = offsets + NN + 1;                    // NE
    int* pk     = csr + NE;                            // NE staging
    const int GEMM_BLOCKS = (NN + 31) / 32;            // 1563

    // zero gcount + g in one shot (contiguous)
    hipMemsetAsync(gcount, 0, (NCB + NG * 128) * 4, stream);

    // layer-1 GEMM+logits co-dispatched with coarse histogram
    gemm_att_k<128, 32, true><<<GEMM_BLOCKS + HB, 256, 0, stream>>>(
        x, W1, as1, ad1, Hb, as_, ad_, GEMM_BLOCKS, edst, gcount);
    cscan_k<<<1, 256, 0, stream>>>(gcount, cbase, gcur);
    parta_k<<<(NE + EPB_A - 1) / EPB_A, 256, 0, stream>>>(esrc, edst, gcur, pk);
    partb_k<<<NCB, 256, 0, stream>>>(pk, cbase, offsets, csr);
    node_agg_k<32, true><<<NN, 64, 0, stream>>>(offsets, csr, as_, ad_, Hb, b1, B0);

    gemm_att_k<32, 64, false><<<GEMM_BLOCKS, 256, 0, stream>>>(
        B0, W2, as2, ad2, Hb, as_, ad_, GEMM_BLOCKS, nullptr, nullptr);
    node_agg_k<64, true><<<NN, 64, 0, stream>>>(offsets, csr, as_, ad_, Hb, b2, B1);

    gemm_att_k<64, 128, false><<<GEMM_BLOCKS, 256, 0, stream>>>(
        B1, W3, as3, ad3, Hb, as_, ad_, GEMM_BLOCKS, nullptr, nullptr);
    node_agg_k<128, false><<<NN, 64, 0, stream>>>(offsets, csr, as_, ad_, Hb, b3, B0);

    pool_k<<<(NN + 127) / 128, 128, 0, stream>>>(B0, batch, g, 128);
    head_k<<<1, 256, 0, stream>>>(g, l1W, l1b, l2W, l2b, out);
}